// Round 12
// baseline (464.105 us; speedup 1.0000x reference)
//
#include <hip/hip_runtime.h>
#include <hip/hip_cooperative_groups.h>
#include <cstddef>

namespace cg = cooperative_groups;

#define NN 12288
#define FD 512
#define H1 32
#define H2 16
#define CAP 80
#define GEMM_BLOCKS 192

// adj tiling for mega kernel
#define TI 64
#define TJ 256
#define NTI (NN / TI)       // 192
#define NTJ (NN / TJ)       // 48
#define NTILES (NTI * NTJ)  // 9216

typedef float floatx4 __attribute__((ext_vector_type(4)));
typedef float floatx2 __attribute__((ext_vector_type(2)));

// ===================== cooperative mega kernel: whole VGAE in 1 dispatch =====================
__global__ __launch_bounds__(256, 4) void k_mega(
    const float* __restrict__ feat, const float* __restrict__ W1,
    const int* __restrict__ src, const int* __restrict__ dst,
    const float* __restrict__ b1,
    const float* __restrict__ W2, const float* __restrict__ b2,
    const float* __restrict__ W3, const float* __restrict__ b3,
    int* __restrict__ cnt, int* __restrict__ deg_out, int* __restrict__ bucket,
    float* __restrict__ P, float* __restrict__ h1s,
    float* __restrict__ mu, float* __restrict__ lv,
    float* __restrict__ adj, int E)
{
    cg::grid_group grid = cg::this_grid();
    __shared__ float LDS[5120]; // 20 KB, reused per phase
    const int tid = threadIdx.x;
    const int nb = gridDim.x;

    // ---- phase 0: zero cnt + deg_out (contiguous 2*NN ints) ----
    for (int i = blockIdx.x * 256 + tid; i < 2 * NN; i += nb * 256) cnt[i] = 0;
    grid.sync();

    // ---- phase 1: P = feat @ W1 (W1 from L2, no LDS)  +  edge count/bucket pass ----
    {
        const int lane = tid & 63;
        const int wv   = tid >> 6;      // wave 0..3
        const int j    = lane & 31;     // output col
        const int sub  = lane >> 5;     // row subgroup 0/1
        for (int rb = blockIdx.x; rb < NN / 32; rb += nb) {
            int r0 = rb * 32 + wv * 8 + sub * 4;
            float a0 = 0, a1 = 0, a2 = 0, a3 = 0;
            const float4* f0 = (const float4*)(feat + (size_t)r0 * FD);
            const float4* f1 = (const float4*)(feat + (size_t)(r0 + 1) * FD);
            const float4* f2 = (const float4*)(feat + (size_t)(r0 + 2) * FD);
            const float4* f3 = (const float4*)(feat + (size_t)(r0 + 3) * FD);
#pragma unroll 4
            for (int k4 = 0; k4 < FD / 4; ++k4) {
                float4 fa = f0[k4], fb = f1[k4], fc = f2[k4], fd = f3[k4];
                float w0 = W1[(k4 * 4 + 0) * H1 + j];
                float w1 = W1[(k4 * 4 + 1) * H1 + j];
                float w2 = W1[(k4 * 4 + 2) * H1 + j];
                float w3 = W1[(k4 * 4 + 3) * H1 + j];
                a0 += fa.x * w0 + fa.y * w1 + fa.z * w2 + fa.w * w3;
                a1 += fb.x * w0 + fb.y * w1 + fb.z * w2 + fb.w * w3;
                a2 += fc.x * w0 + fc.y * w1 + fc.z * w2 + fc.w * w3;
                a3 += fd.x * w0 + fd.y * w1 + fd.z * w2 + fd.w * w3;
            }
            P[(size_t)r0 * H1 + j]       = a0;
            P[(size_t)(r0 + 1) * H1 + j] = a1;
            P[(size_t)(r0 + 2) * H1 + j] = a2;
            P[(size_t)(r0 + 3) * H1 + j] = a3;
        }
        // edges (independent of gemm, same phase)
        int E4 = E >> 2;
        for (int t = blockIdx.x * 256 + tid; t < E4; t += nb * 256) {
            int4 s = ((const int4*)src)[t];
            int4 d = ((const int4*)dst)[t];
            atomicAdd(&deg_out[s.x], 1); atomicAdd(&deg_out[s.y], 1);
            atomicAdd(&deg_out[s.z], 1); atomicAdd(&deg_out[s.w], 1);
            int sl;
            sl = atomicAdd(&cnt[d.x], 1); if (sl < CAP) bucket[d.x * CAP + sl] = s.x;
            sl = atomicAdd(&cnt[d.y], 1); if (sl < CAP) bucket[d.y * CAP + sl] = s.y;
            sl = atomicAdd(&cnt[d.z], 1); if (sl < CAP) bucket[d.z * CAP + sl] = s.z;
            sl = atomicAdd(&cnt[d.w], 1); if (sl < CAP) bucket[d.w * CAP + sl] = s.w;
        }
        if (blockIdx.x == 0 && tid == 0) {
            for (int e = (E >> 2) << 2; e < E; ++e) {
                atomicAdd(&deg_out[src[e]], 1);
                int d = dst[e];
                int sl = atomicAdd(&cnt[d], 1);
                if (sl < CAP) bucket[d * CAP + sl] = src[e];
            }
        }
    }
    grid.sync();

    // ---- phase 2: agg1 -> h1s (bucket pull, inline norms, ReLU) ----
    {
        const int rl = tid >> 5, j = tid & 31;
        for (int g = blockIdx.x; g < NN / 8; g += nb) {
            int r = g * 8 + rl;
            int deg = cnt[r];
            const int* bk = bucket + (size_t)r * CAP;
            float sA = 0.0f, sB = 0.0f;
            int e = 0;
            for (; e + 3 < deg; e += 4) {
                int s0 = bk[e], s1 = bk[e + 1], s2 = bk[e + 2], s3 = bk[e + 3];
                float w0 = rsqrtf((float)deg_out[s0]), w1 = rsqrtf((float)deg_out[s1]);
                float w2 = rsqrtf((float)deg_out[s2]), w3 = rsqrtf((float)deg_out[s3]);
                sA += w0 * P[(size_t)s0 * H1 + j] + w1 * P[(size_t)s1 * H1 + j];
                sB += w2 * P[(size_t)s2 * H1 + j] + w3 * P[(size_t)s3 * H1 + j];
            }
            for (; e < deg; ++e) {
                int s0 = bk[e];
                sA += rsqrtf((float)deg_out[s0]) * P[(size_t)s0 * H1 + j];
            }
            float h = fmaxf((sA + sB) * rsqrtf((float)deg) + b1[j], 0.0f);
            h1s[(size_t)r * H1 + j] = h * rsqrtf((float)deg_out[r]);
        }
    }
    grid.sync();

    // ---- phase 3: agg2 -> mu, lv ----
    {
        float* W2l = LDS;          // 512
        float* W3l = LDS + 512;    // 512
        float* S   = LDS + 1024;   // 8*32
        for (int t = tid; t < H1 * H2; t += 256) { W2l[t] = W2[t]; W3l[t] = W3[t]; }
        const int rl = tid >> 5, j = tid & 31;
        const int rr = tid >> 5, c = tid & 15;
        const bool is_lv = (tid & 16) != 0;
        for (int g = blockIdx.x; g < NN / 8; g += nb) {
            int r = g * 8 + rl;
            int deg = cnt[r];
            const int* bk = bucket + (size_t)r * CAP;
            float sA = 0.0f, sB = 0.0f;
            int e = 0;
            for (; e + 3 < deg; e += 4) {
                int s0 = bk[e], s1 = bk[e + 1], s2 = bk[e + 2], s3 = bk[e + 3];
                sA += h1s[(size_t)s0 * H1 + j] + h1s[(size_t)s1 * H1 + j];
                sB += h1s[(size_t)s2 * H1 + j] + h1s[(size_t)s3 * H1 + j];
            }
            for (; e < deg; ++e) sA += h1s[(size_t)bk[e] * H1 + j];
            __syncthreads();
            S[rl * H1 + j] = (sA + sB) * rsqrtf((float)deg);
            __syncthreads();
            const float* W = is_lv ? W3l : W2l;
            float acc = is_lv ? b3[c] : b2[c];
#pragma unroll
            for (int k = 0; k < H1; ++k) acc += S[rr * H1 + k] * W[k * H2 + c];
            float* o = is_lv ? lv : mu;
            o[(size_t)(g * 8 + rr) * H2 + c] = acc;
        }
    }
    grid.sync();

    // ---- phase 4: adj = mu @ mu^T, grid-stride 64x256 tiles ----
    {
        float* Alt = LDS;          // [16][64]
        float* Blt = LDS + TI * H2; // [16][256]
        const int tx = tid & 15, ty = tid >> 4;
        for (int tile = blockIdx.x; tile < NTILES; tile += nb) {
            int i0 = (tile % NTI) * TI;
            int j0 = (tile / NTI) * TJ;
            __syncthreads(); // previous tile's LDS reads done
            {
                int row = tid >> 2, seg = tid & 3;
                float4 a = *(const float4*)&mu[(size_t)(i0 + row) * H2 + seg * 4];
                Alt[(seg * 4 + 0) * TI + row] = a.x;
                Alt[(seg * 4 + 1) * TI + row] = a.y;
                Alt[(seg * 4 + 2) * TI + row] = a.z;
                Alt[(seg * 4 + 3) * TI + row] = a.w;
                float4 b0 = *(const float4*)&mu[(size_t)(j0 + tid) * H2 + 0];
                float4 b1 = *(const float4*)&mu[(size_t)(j0 + tid) * H2 + 4];
                float4 b2 = *(const float4*)&mu[(size_t)(j0 + tid) * H2 + 8];
                float4 b3 = *(const float4*)&mu[(size_t)(j0 + tid) * H2 + 12];
                Blt[0 * TJ + tid] = b0.x;  Blt[1 * TJ + tid] = b0.y;
                Blt[2 * TJ + tid] = b0.z;  Blt[3 * TJ + tid] = b0.w;
                Blt[4 * TJ + tid] = b1.x;  Blt[5 * TJ + tid] = b1.y;
                Blt[6 * TJ + tid] = b1.z;  Blt[7 * TJ + tid] = b1.w;
                Blt[8 * TJ + tid] = b2.x;  Blt[9 * TJ + tid] = b2.y;
                Blt[10 * TJ + tid] = b2.z; Blt[11 * TJ + tid] = b2.w;
                Blt[12 * TJ + tid] = b3.x; Blt[13 * TJ + tid] = b3.y;
                Blt[14 * TJ + tid] = b3.z; Blt[15 * TJ + tid] = b3.w;
            }
            __syncthreads();

            floatx2 acc2[4][8] = {};
#pragma unroll 2
            for (int k = 0; k < H2; ++k) {
                floatx4 av4 = *(const floatx4*)&Alt[k * TI + ty * 4];
                float a[4] = {av4.x, av4.y, av4.z, av4.w};
                floatx2 bp[8];
#pragma unroll
                for (int g = 0; g < 4; ++g) {
                    floatx4 b = *(const floatx4*)&Blt[k * TJ + g * 64 + tx * 4];
                    bp[2 * g]     = (floatx2){b.x, b.y};
                    bp[2 * g + 1] = (floatx2){b.z, b.w};
                }
#pragma unroll
                for (int ii = 0; ii < 4; ++ii) {
                    floatx2 avv = (floatx2){a[ii], a[ii]};
#pragma unroll
                    for (int jp = 0; jp < 8; ++jp)
                        acc2[ii][jp] = __builtin_elementwise_fma(avv, bp[jp], acc2[ii][jp]);
                }
            }
#pragma unroll
            for (int ii = 0; ii < 4; ++ii) {
                size_t row = (size_t)(i0 + ty * 4 + ii);
#pragma unroll
                for (int g = 0; g < 4; ++g) {
                    float4 v = make_float4(acc2[ii][2 * g].x, acc2[ii][2 * g].y,
                                           acc2[ii][2 * g + 1].x, acc2[ii][2 * g + 1].y);
                    *(float4*)&adj[row * NN + j0 + g * 64 + tx * 4] = v;
                }
            }
        }
    }
}

// ===================== fallback: R10 kernels (proven 219 µs path) =====================
__global__ __launch_bounds__(256) void k_fused1(const float* __restrict__ feat,
                                                const float* __restrict__ W1,
                                                float* __restrict__ P,
                                                const int* __restrict__ src,
                                                const int* __restrict__ dst,
                                                int* __restrict__ cnt,
                                                int* __restrict__ deg_out,
                                                int* __restrict__ bucket, int E) {
    if (blockIdx.x < GEMM_BLOCKS) {
        __shared__ float Wlds[FD * H1];
        int tid = threadIdx.x;
        for (int t = tid; t < FD * H1 / 4; t += 256) ((float4*)Wlds)[t] = ((const float4*)W1)[t];
        __syncthreads();
        int row = blockIdx.x * 64 + (tid >> 2);
        int cg  = (tid & 3) * 8;
        float acc[8] = {};
        const float4* f4 = (const float4*)(feat + (size_t)row * FD);
#pragma unroll 4
        for (int k4 = 0; k4 < FD / 4; ++k4) {
            float4 f = f4[k4];
            const float* w = &Wlds[(k4 * 4) * H1 + cg];
#pragma unroll
            for (int j = 0; j < 8; ++j)
                acc[j] += f.x * w[j] + f.y * w[H1 + j] + f.z * w[2 * H1 + j] + f.w * w[3 * H1 + j];
        }
#pragma unroll
        for (int j = 0; j < 8; ++j) P[(size_t)row * H1 + cg + j] = acc[j];
    } else {
        int t = (blockIdx.x - GEMM_BLOCKS) * 256 + threadIdx.x;
        int E4 = E >> 2;
        if (t < E4) {
            int4 s = ((const int4*)src)[t];
            int4 d = ((const int4*)dst)[t];
            atomicAdd(&deg_out[s.x], 1); atomicAdd(&deg_out[s.y], 1);
            atomicAdd(&deg_out[s.z], 1); atomicAdd(&deg_out[s.w], 1);
            int sl;
            sl = atomicAdd(&cnt[d.x], 1); if (sl < CAP) bucket[d.x * CAP + sl] = s.x;
            sl = atomicAdd(&cnt[d.y], 1); if (sl < CAP) bucket[d.y * CAP + sl] = s.y;
            sl = atomicAdd(&cnt[d.z], 1); if (sl < CAP) bucket[d.z * CAP + sl] = s.z;
            sl = atomicAdd(&cnt[d.w], 1); if (sl < CAP) bucket[d.w * CAP + sl] = s.w;
        }
        if (t == 0) {
            for (int e = E4 * 4; e < E; ++e) {
                atomicAdd(&deg_out[src[e]], 1);
                int d = dst[e];
                int sl = atomicAdd(&cnt[d], 1);
                if (sl < CAP) bucket[d * CAP + sl] = src[e];
            }
        }
    }
}

__global__ __launch_bounds__(256) void k_agg1(const int* __restrict__ cnt,
                                              const int* __restrict__ deg_out,
                                              const int* __restrict__ bucket,
                                              const float* __restrict__ P,
                                              const float* __restrict__ b1,
                                              float* __restrict__ h1s) {
    int r = blockIdx.x * 8 + (threadIdx.x >> 5);
    int j = threadIdx.x & 31;
    int deg = cnt[r];
    const int* bk = bucket + (size_t)r * CAP;
    float sA = 0.0f, sB = 0.0f;
    int e = 0;
    for (; e + 3 < deg; e += 4) {
        int s0 = bk[e], s1 = bk[e + 1], s2 = bk[e + 2], s3 = bk[e + 3];
        float w0 = rsqrtf((float)deg_out[s0]), w1 = rsqrtf((float)deg_out[s1]);
        float w2 = rsqrtf((float)deg_out[s2]), w3 = rsqrtf((float)deg_out[s3]);
        sA += w0 * P[(size_t)s0 * H1 + j] + w1 * P[(size_t)s1 * H1 + j];
        sB += w2 * P[(size_t)s2 * H1 + j] + w3 * P[(size_t)s3 * H1 + j];
    }
    for (; e < deg; ++e) { int s0 = bk[e]; sA += rsqrtf((float)deg_out[s0]) * P[(size_t)s0 * H1 + j]; }
    float h = fmaxf((sA + sB) * rsqrtf((float)deg) + b1[j], 0.0f);
    h1s[(size_t)r * H1 + j] = h * rsqrtf((float)deg_out[r]);
}

__global__ __launch_bounds__(256) void k_agg2(const int* __restrict__ cnt,
                                              const int* __restrict__ bucket,
                                              const float* __restrict__ h1s,
                                              const float* __restrict__ W2, const float* __restrict__ b2,
                                              const float* __restrict__ W3, const float* __restrict__ b3,
                                              float* __restrict__ mu, float* __restrict__ lv) {
    __shared__ float W2l[H1 * H2], W3l[H1 * H2];
    __shared__ float S[8][H1];
    int tid = threadIdx.x;
    for (int t = tid; t < H1 * H2; t += 256) { W2l[t] = W2[t]; W3l[t] = W3[t]; }
    int r0 = blockIdx.x * 8;
    int rl = tid >> 5, j = tid & 31;
    int r = r0 + rl;
    int deg = cnt[r];
    const int* bk = bucket + (size_t)r * CAP;
    float sA = 0.0f, sB = 0.0f;
    int e = 0;
    for (; e + 3 < deg; e += 4) {
        int s0 = bk[e], s1 = bk[e + 1], s2 = bk[e + 2], s3 = bk[e + 3];
        sA += h1s[(size_t)s0 * H1 + j] + h1s[(size_t)s1 * H1 + j];
        sB += h1s[(size_t)s2 * H1 + j] + h1s[(size_t)s3 * H1 + j];
    }
    for (; e < deg; ++e) sA += h1s[(size_t)bk[e] * H1 + j];
    S[rl][j] = (sA + sB) * rsqrtf((float)deg);
    __syncthreads();
    int rr = tid >> 5, c = tid & 15;
    bool is_lv = (tid & 16) != 0;
    const float* W = is_lv ? W3l : W2l;
    float acc = is_lv ? b3[c] : b2[c];
#pragma unroll
    for (int k = 0; k < H1; ++k) acc += S[rr][k] * W[k * H2 + c];
    float* o = is_lv ? lv : mu;
    o[(size_t)(r0 + rr) * H2 + c] = acc;
}

#define FTI 128
#define FTJ 256
__global__ __launch_bounds__(256, 2) void k_adj(const float* __restrict__ mu, float* __restrict__ out) {
    __shared__ float Alt[H2][FTI];
    __shared__ float Blt[H2][FTJ];
    int tid = threadIdx.x;
    int i0 = blockIdx.y * FTI;
    int j0 = blockIdx.x * FTJ;
    {
        int row = tid >> 1;
        int h8  = (tid & 1) * 8;
        float4 a0 = *(const float4*)&mu[(size_t)(i0 + row) * H2 + h8];
        float4 a1 = *(const float4*)&mu[(size_t)(i0 + row) * H2 + h8 + 4];
        Alt[h8 + 0][row] = a0.x; Alt[h8 + 1][row] = a0.y; Alt[h8 + 2][row] = a0.z; Alt[h8 + 3][row] = a0.w;
        Alt[h8 + 4][row] = a1.x; Alt[h8 + 5][row] = a1.y; Alt[h8 + 6][row] = a1.z; Alt[h8 + 7][row] = a1.w;
        float4 b0 = *(const float4*)&mu[(size_t)(j0 + tid) * H2 + 0];
        float4 b1 = *(const float4*)&mu[(size_t)(j0 + tid) * H2 + 4];
        float4 b2 = *(const float4*)&mu[(size_t)(j0 + tid) * H2 + 8];
        float4 b3 = *(const float4*)&mu[(size_t)(j0 + tid) * H2 + 12];
        Blt[0][tid] = b0.x; Blt[1][tid] = b0.y; Blt[2][tid] = b0.z; Blt[3][tid] = b0.w;
        Blt[4][tid] = b1.x; Blt[5][tid] = b1.y; Blt[6][tid] = b1.z; Blt[7][tid] = b1.w;
        Blt[8][tid] = b2.x; Blt[9][tid] = b2.y; Blt[10][tid] = b2.z; Blt[11][tid] = b2.w;
        Blt[12][tid] = b3.x; Blt[13][tid] = b3.y; Blt[14][tid] = b3.z; Blt[15][tid] = b3.w;
    }
    __syncthreads();
    int tx = tid & 15;
    int ty = tid >> 4;
    floatx2 acc2[8][8] = {};
#pragma unroll 2
    for (int k = 0; k < H2; ++k) {
        floatx4 a0 = *(const floatx4*)&Alt[k][ty * 8];
        floatx4 a1 = *(const floatx4*)&Alt[k][ty * 8 + 4];
        float a[8] = {a0.x, a0.y, a0.z, a0.w, a1.x, a1.y, a1.z, a1.w};
        floatx2 bp[8];
#pragma unroll
        for (int g = 0; g < 4; ++g) {
            floatx4 b = *(const floatx4*)&Blt[k][g * 64 + tx * 4];
            bp[2 * g]     = (floatx2){b.x, b.y};
            bp[2 * g + 1] = (floatx2){b.z, b.w};
        }
#pragma unroll
        for (int ii = 0; ii < 8; ++ii) {
            floatx2 av = (floatx2){a[ii], a[ii]};
#pragma unroll
            for (int jp = 0; jp < 8; ++jp)
                acc2[ii][jp] = __builtin_elementwise_fma(av, bp[jp], acc2[ii][jp]);
        }
    }
#pragma unroll
    for (int ii = 0; ii < 8; ++ii) {
        size_t row = (size_t)(i0 + ty * 8 + ii);
#pragma unroll
        for (int g = 0; g < 4; ++g) {
            float4 v = make_float4(acc2[ii][2 * g].x, acc2[ii][2 * g].y,
                                   acc2[ii][2 * g + 1].x, acc2[ii][2 * g + 1].y);
            *(float4*)&out[row * NN + j0 + g * 64 + tx * 4] = v;
        }
    }
}

extern "C" void kernel_launch(void* const* d_in, const int* in_sizes, int n_in,
                              void* d_out, int out_size, void* d_ws, size_t ws_size,
                              hipStream_t stream) {
    const float* feat = (const float*)d_in[0];
    const int*   src  = (const int*)d_in[1];
    const int*   dst  = (const int*)d_in[2];
    const float* W1   = (const float*)d_in[3];
    const float* b1   = (const float*)d_in[4];
    const float* W2   = (const float*)d_in[5];
    const float* b2   = (const float*)d_in[6];
    const float* W3   = (const float*)d_in[7];
    const float* b3   = (const float*)d_in[8];
    int E = in_sizes[1]; // 405504

    int* iws = (int*)d_ws;
    int* cnt     = iws;                 // [NN]
    int* deg_out = iws + NN;            // [NN]
    int* bucket  = iws + 2 * NN;        // [NN*CAP]
    float* fws = (float*)(iws + 2 * NN + NN * CAP);
    float* P   = fws;                   // [NN*H1]
    float* h1s = fws + NN * H1;         // [NN*H1]

    float* adj = (float*)d_out;             // [NN*NN]
    float* mu  = adj + (size_t)NN * NN;     // [NN*H2]
    float* lv  = mu + (size_t)NN * H2;      // [NN*H2]

    // size the cooperative grid to guaranteed co-residency
    int dev = 0;
    hipGetDevice(&dev);
    int nCU = 0;
    hipDeviceGetAttribute(&nCU, hipDeviceAttributeMultiprocessorCount, dev);
    int bpc = 0;
    hipOccupancyMaxActiveBlocksPerMultiprocessor(&bpc, k_mega, 256, 0);
    if (nCU <= 0) nCU = 256;
    if (bpc <= 0) bpc = 1;
    if (bpc > 4) bpc = 4;
    int nb = nCU * bpc;

    void* args[] = { (void*)&feat, (void*)&W1, (void*)&src, (void*)&dst, (void*)&b1,
                     (void*)&W2, (void*)&b2, (void*)&W3, (void*)&b3,
                     (void*)&cnt, (void*)&deg_out, (void*)&bucket,
                     (void*)&P, (void*)&h1s, (void*)&mu, (void*)&lv, (void*)&adj, (void*)&E };
    hipError_t err = hipLaunchCooperativeKernel((void*)k_mega, dim3(nb), dim3(256),
                                                args, 0, stream);
    if (err != hipSuccess) {
        // fallback: proven R10 5-dispatch path
        hipMemsetAsync(iws, 0, 2 * NN * sizeof(int), stream);
        int eb4 = ((E >> 2) + 255) / 256;
        k_fused1<<<GEMM_BLOCKS + eb4, 256, 0, stream>>>(feat, W1, P, src, dst,
                                                        cnt, deg_out, bucket, E);
        k_agg1<<<NN / 8, 256, 0, stream>>>(cnt, deg_out, bucket, P, b1, h1s);
        k_agg2<<<NN / 8, 256, 0, stream>>>(cnt, bucket, h1s, W2, b2, W3, b3, mu, lv);
        dim3 grid(NN / FTJ, NN / FTI);
        k_adj<<<grid, 256, 0, stream>>>(mu, adj);
    }
}

// Round 13
// 233.199 us; speedup vs baseline: 1.9902x; 1.9902x over previous
//
#include <hip/hip_runtime.h>
#include <cstddef>

#define NN 12288
#define FD 512
#define H1 32
#define H2 16
#define CAP 80
#define GEMM_BLOCKS 192

typedef float floatx4 __attribute__((ext_vector_type(4)));
typedef float floatx2 __attribute__((ext_vector_type(2)));

// ---------------- fused: P = feat @ W1  ||  edge pass (count + bucket scatter) ----
__global__ __launch_bounds__(256) void k_fused1(const float* __restrict__ feat,
                                                const float* __restrict__ W1,
                                                float* __restrict__ P,
                                                const int* __restrict__ src,
                                                const int* __restrict__ dst,
                                                int* __restrict__ cnt,
                                                int* __restrict__ deg_out,
                                                int* __restrict__ bucket, int E) {
    if (blockIdx.x < GEMM_BLOCKS) {
        __shared__ float Wlds[FD * H1]; // 64 KB, k-major [k][c]
        int tid = threadIdx.x;
        for (int t = tid; t < FD * H1 / 4; t += 256) {
            ((float4*)Wlds)[t] = ((const float4*)W1)[t];
        }
        __syncthreads();

        int row = blockIdx.x * 64 + (tid >> 2);
        int cg  = (tid & 3) * 8;
        float acc[8] = {};
        const float4* f4 = (const float4*)(feat + (size_t)row * FD);
#pragma unroll 4
        for (int k4 = 0; k4 < FD / 4; ++k4) {
            float4 f = f4[k4];
            const float* w = &Wlds[(k4 * 4) * H1 + cg];
#pragma unroll
            for (int j = 0; j < 8; ++j) {
                acc[j] += f.x * w[j] + f.y * w[H1 + j] + f.z * w[2 * H1 + j] + f.w * w[3 * H1 + j];
            }
        }
#pragma unroll
        for (int j = 0; j < 8; ++j) P[(size_t)row * H1 + cg + j] = acc[j];
    } else {
        int t = (blockIdx.x - GEMM_BLOCKS) * 256 + threadIdx.x;
        int E4 = E >> 2;
        if (t < E4) {
            int4 s = ((const int4*)src)[t];
            int4 d = ((const int4*)dst)[t];
            atomicAdd(&deg_out[s.x], 1); atomicAdd(&deg_out[s.y], 1);
            atomicAdd(&deg_out[s.z], 1); atomicAdd(&deg_out[s.w], 1);
            int sl;
            sl = atomicAdd(&cnt[d.x], 1); if (sl < CAP) bucket[d.x * CAP + sl] = s.x;
            sl = atomicAdd(&cnt[d.y], 1); if (sl < CAP) bucket[d.y * CAP + sl] = s.y;
            sl = atomicAdd(&cnt[d.z], 1); if (sl < CAP) bucket[d.z * CAP + sl] = s.z;
            sl = atomicAdd(&cnt[d.w], 1); if (sl < CAP) bucket[d.w * CAP + sl] = s.w;
        }
        if (t == 0) { // tail (E%4)
            for (int e = E4 * 4; e < E; ++e) {
                atomicAdd(&deg_out[src[e]], 1);
                int d = dst[e];
                int sl = atomicAdd(&cnt[d], 1);
                if (sl < CAP) bucket[d * CAP + sl] = src[e];
            }
        }
    }
}

// ---------------- agg1: bucket pull, inline norms, fused ReLU epilogue ----------------
__global__ __launch_bounds__(256) void k_agg1(const int* __restrict__ cnt,
                                              const int* __restrict__ deg_out,
                                              const int* __restrict__ bucket,
                                              const float* __restrict__ P,
                                              const float* __restrict__ b1,
                                              float* __restrict__ h1s) {
    int r = blockIdx.x * 8 + (threadIdx.x >> 5);
    int j = threadIdx.x & 31;
    int deg = cnt[r];
    const int* bk = bucket + (size_t)r * CAP;
    float sA = 0.0f, sB = 0.0f;
    int e = 0;
    for (; e + 3 < deg; e += 4) {
        int s0 = bk[e], s1 = bk[e + 1], s2 = bk[e + 2], s3 = bk[e + 3];
        float w0 = rsqrtf((float)deg_out[s0]), w1 = rsqrtf((float)deg_out[s1]);
        float w2 = rsqrtf((float)deg_out[s2]), w3 = rsqrtf((float)deg_out[s3]);
        sA += w0 * P[(size_t)s0 * H1 + j] + w1 * P[(size_t)s1 * H1 + j];
        sB += w2 * P[(size_t)s2 * H1 + j] + w3 * P[(size_t)s3 * H1 + j];
    }
    for (; e < deg; ++e) {
        int s0 = bk[e];
        sA += rsqrtf((float)deg_out[s0]) * P[(size_t)s0 * H1 + j];
    }
    float h = fmaxf((sA + sB) * rsqrtf((float)deg) + b1[j], 0.0f);
    h1s[(size_t)r * H1 + j] = h * rsqrtf((float)deg_out[r]);
}

// ---------------- agg2: bucket pull + inline norm + fused mu/logvar projection ------
__global__ __launch_bounds__(256) void k_agg2(const int* __restrict__ cnt,
                                              const int* __restrict__ bucket,
                                              const float* __restrict__ h1s,
                                              const float* __restrict__ W2, const float* __restrict__ b2,
                                              const float* __restrict__ W3, const float* __restrict__ b3,
                                              float* __restrict__ mu, float* __restrict__ lv) {
    __shared__ float W2l[H1 * H2], W3l[H1 * H2];
    __shared__ float S[8][H1];
    int tid = threadIdx.x;
    for (int t = tid; t < H1 * H2; t += 256) { W2l[t] = W2[t]; W3l[t] = W3[t]; }

    int r0 = blockIdx.x * 8;
    int rl = tid >> 5, j = tid & 31;
    int r = r0 + rl;
    int deg = cnt[r];
    const int* bk = bucket + (size_t)r * CAP;
    float sA = 0.0f, sB = 0.0f;
    int e = 0;
    for (; e + 3 < deg; e += 4) {
        int s0 = bk[e], s1 = bk[e + 1], s2 = bk[e + 2], s3 = bk[e + 3];
        sA += h1s[(size_t)s0 * H1 + j] + h1s[(size_t)s1 * H1 + j];
        sB += h1s[(size_t)s2 * H1 + j] + h1s[(size_t)s3 * H1 + j];
    }
    for (; e < deg; ++e) sA += h1s[(size_t)bk[e] * H1 + j];
    S[rl][j] = (sA + sB) * rsqrtf((float)deg);
    __syncthreads();

    int rr = tid >> 5;
    int c = tid & 15;
    bool is_lv = (tid & 16) != 0;
    const float* W = is_lv ? W3l : W2l;
    float acc = is_lv ? b3[c] : b2[c];
#pragma unroll
    for (int k = 0; k < H1; ++k) acc += S[rr][k] * W[k * H2 + c];
    float* o = is_lv ? lv : mu;
    o[(size_t)(r0 + rr) * H2 + c] = acc;
}

// ---------------- adj = mu @ mu^T, 128-row strip x 12 pipelined 256-col tiles --------
#define TI 128
#define TJ 256
#define CHUNK 12   // tiles per block; grid = (4, 96) = 384 blocks, 1.5 MB stored each
__global__ __launch_bounds__(256, 2) void k_adj(const float* __restrict__ mu, float* __restrict__ out) {
    __shared__ float Alt[H2][TI]; // k-major
    __shared__ float Blt[H2][TJ];
    int tid = threadIdx.x;
    int i0 = blockIdx.y * TI;
    int jbase = blockIdx.x * (TJ * CHUNK);

    // A: load once per block
    {
        int row = tid >> 1;
        int h8  = (tid & 1) * 8;
        float4 a0 = *(const float4*)&mu[(size_t)(i0 + row) * H2 + h8];
        float4 a1 = *(const float4*)&mu[(size_t)(i0 + row) * H2 + h8 + 4];
        Alt[h8 + 0][row] = a0.x; Alt[h8 + 1][row] = a0.y; Alt[h8 + 2][row] = a0.z; Alt[h8 + 3][row] = a0.w;
        Alt[h8 + 4][row] = a1.x; Alt[h8 + 5][row] = a1.y; Alt[h8 + 6][row] = a1.z; Alt[h8 + 7][row] = a1.w;
    }
    // B tile 0: load regs + write LDS
    float4 pb0, pb1, pb2, pb3;
    {
        const float* br = &mu[(size_t)(jbase + tid) * H2];
        pb0 = *(const float4*)&br[0];  pb1 = *(const float4*)&br[4];
        pb2 = *(const float4*)&br[8];  pb3 = *(const float4*)&br[12];
        Blt[0][tid] = pb0.x;  Blt[1][tid] = pb0.y;  Blt[2][tid] = pb0.z;  Blt[3][tid] = pb0.w;
        Blt[4][tid] = pb1.x;  Blt[5][tid] = pb1.y;  Blt[6][tid] = pb1.z;  Blt[7][tid] = pb1.w;
        Blt[8][tid] = pb2.x;  Blt[9][tid] = pb2.y;  Blt[10][tid] = pb2.z; Blt[11][tid] = pb2.w;
        Blt[12][tid] = pb3.x; Blt[13][tid] = pb3.y; Blt[14][tid] = pb3.z; Blt[15][tid] = pb3.w;
    }
    __syncthreads();

    int tx = tid & 15;
    int ty = tid >> 4;
    for (int t = 0; t < CHUNK; ++t) {
        int j0 = jbase + t * TJ;
        // prefetch next B tile into registers (latency hides under compute+store)
        if (t + 1 < CHUNK) {
            const float* br = &mu[(size_t)(j0 + TJ + tid) * H2];
            pb0 = *(const float4*)&br[0];  pb1 = *(const float4*)&br[4];
            pb2 = *(const float4*)&br[8];  pb3 = *(const float4*)&br[12];
        }

        floatx2 acc2[8][8] = {};
#pragma unroll 2
        for (int k = 0; k < H2; ++k) {
            floatx4 a0 = *(const floatx4*)&Alt[k][ty * 8];
            floatx4 a1 = *(const floatx4*)&Alt[k][ty * 8 + 4];
            float a[8] = {a0.x, a0.y, a0.z, a0.w, a1.x, a1.y, a1.z, a1.w};
            floatx2 bp[8];
#pragma unroll
            for (int g = 0; g < 4; ++g) {
                floatx4 b = *(const floatx4*)&Blt[k][g * 64 + tx * 4];
                bp[2 * g]     = (floatx2){b.x, b.y};
                bp[2 * g + 1] = (floatx2){b.z, b.w};
            }
#pragma unroll
            for (int ii = 0; ii < 8; ++ii) {
                floatx2 av = (floatx2){a[ii], a[ii]};
#pragma unroll
                for (int jp = 0; jp < 8; ++jp)
                    acc2[ii][jp] = __builtin_elementwise_fma(av, bp[jp], acc2[ii][jp]);
            }
        }

#pragma unroll
        for (int ii = 0; ii < 8; ++ii) {
            size_t row = (size_t)(i0 + ty * 8 + ii);
#pragma unroll
            for (int g = 0; g < 4; ++g) {
                float4 v = make_float4(acc2[ii][2 * g].x, acc2[ii][2 * g].y,
                                       acc2[ii][2 * g + 1].x, acc2[ii][2 * g + 1].y);
                *(float4*)&out[row * NN + j0 + g * 64 + tx * 4] = v;
            }
        }

        if (t + 1 < CHUNK) {
            __syncthreads(); // all compute reads of Blt done
            Blt[0][tid] = pb0.x;  Blt[1][tid] = pb0.y;  Blt[2][tid] = pb0.z;  Blt[3][tid] = pb0.w;
            Blt[4][tid] = pb1.x;  Blt[5][tid] = pb1.y;  Blt[6][tid] = pb1.z;  Blt[7][tid] = pb1.w;
            Blt[8][tid] = pb2.x;  Blt[9][tid] = pb2.y;  Blt[10][tid] = pb2.z; Blt[11][tid] = pb2.w;
            Blt[12][tid] = pb3.x; Blt[13][tid] = pb3.y; Blt[14][tid] = pb3.z; Blt[15][tid] = pb3.w;
            __syncthreads();
        }
    }
}

extern "C" void kernel_launch(void* const* d_in, const int* in_sizes, int n_in,
                              void* d_out, int out_size, void* d_ws, size_t ws_size,
                              hipStream_t stream) {
    const float* feat = (const float*)d_in[0];
    const int*   src  = (const int*)d_in[1];
    const int*   dst  = (const int*)d_in[2];
    const float* W1   = (const float*)d_in[3];
    const float* b1   = (const float*)d_in[4];
    const float* W2   = (const float*)d_in[5];
    const float* b2   = (const float*)d_in[6];
    const float* W3   = (const float*)d_in[7];
    const float* b3   = (const float*)d_in[8];
    int E = in_sizes[1]; // 405504

    int* iws = (int*)d_ws;
    int* cnt     = iws;                 // [NN]
    int* deg_out = iws + NN;            // [NN]
    int* bucket  = iws + 2 * NN;        // [NN*CAP]
    float* fws = (float*)(iws + 2 * NN + NN * CAP);
    float* P   = fws;                   // [NN*H1]
    float* h1s = fws + NN * H1;         // [NN*H1]

    float* adj = (float*)d_out;             // [NN*NN]
    float* mu  = adj + (size_t)NN * NN;     // [NN*H2]
    float* lv  = mu + (size_t)NN * H2;      // [NN*H2]

    hipMemsetAsync(iws, 0, 2 * NN * sizeof(int), stream); // cnt + deg_out

    int eb4 = ((E >> 2) + 255) / 256;
    k_fused1<<<GEMM_BLOCKS + eb4, 256, 0, stream>>>(feat, W1, P, src, dst,
                                                    cnt, deg_out, bucket, E);
    k_agg1<<<NN / 8, 256, 0, stream>>>(cnt, deg_out, bucket, P, b1, h1s);
    k_agg2<<<NN / 8, 256, 0, stream>>>(cnt, bucket, h1s, W2, b2, W3, b3, mu, lv);

    dim3 grid(NN / (TJ * CHUNK), NN / TI); // (4, 96) = 384 blocks
    k_adj<<<grid, 256, 0, stream>>>(mu, adj);
}

// Round 14
// 205.264 us; speedup vs baseline: 2.2610x; 1.1361x over previous
//
#include <hip/hip_runtime.h>
#include <cstddef>

#define NN 12288
#define FD 512
#define H1 32
#define H2 16
#define CAP 80
#define GEMM_BLOCKS 192

typedef float floatx4 __attribute__((ext_vector_type(4)));
typedef float floatx2 __attribute__((ext_vector_type(2)));

// ---------------- fused: P = feat @ W1  ||  edge pass (count + bucket scatter) ----
__global__ __launch_bounds__(256) void k_fused1(const float* __restrict__ feat,
                                                const float* __restrict__ W1,
                                                float* __restrict__ P,
                                                const int* __restrict__ src,
                                                const int* __restrict__ dst,
                                                int* __restrict__ cnt,
                                                int* __restrict__ deg_out,
                                                int* __restrict__ bucket, int E) {
    if (blockIdx.x < GEMM_BLOCKS) {
        __shared__ float Wlds[FD * H1]; // 64 KB, k-major [k][c]
        int tid = threadIdx.x;
        for (int t = tid; t < FD * H1 / 4; t += 256) {
            ((float4*)Wlds)[t] = ((const float4*)W1)[t];
        }
        __syncthreads();

        int row = blockIdx.x * 64 + (tid >> 2);
        int cg  = (tid & 3) * 8;
        float acc[8] = {};
        const float4* f4 = (const float4*)(feat + (size_t)row * FD);
#pragma unroll 4
        for (int k4 = 0; k4 < FD / 4; ++k4) {
            float4 f = f4[k4];
            const float* w = &Wlds[(k4 * 4) * H1 + cg];
#pragma unroll
            for (int j = 0; j < 8; ++j) {
                acc[j] += f.x * w[j] + f.y * w[H1 + j] + f.z * w[2 * H1 + j] + f.w * w[3 * H1 + j];
            }
        }
#pragma unroll
        for (int j = 0; j < 8; ++j) P[(size_t)row * H1 + cg + j] = acc[j];
    } else {
        int t = (blockIdx.x - GEMM_BLOCKS) * 256 + threadIdx.x;
        int E4 = E >> 2;
        if (t < E4) {
            int4 s = ((const int4*)src)[t];
            int4 d = ((const int4*)dst)[t];
            atomicAdd(&deg_out[s.x], 1); atomicAdd(&deg_out[s.y], 1);
            atomicAdd(&deg_out[s.z], 1); atomicAdd(&deg_out[s.w], 1);
            int sl;
            sl = atomicAdd(&cnt[d.x], 1); if (sl < CAP) bucket[d.x * CAP + sl] = s.x;
            sl = atomicAdd(&cnt[d.y], 1); if (sl < CAP) bucket[d.y * CAP + sl] = s.y;
            sl = atomicAdd(&cnt[d.z], 1); if (sl < CAP) bucket[d.z * CAP + sl] = s.z;
            sl = atomicAdd(&cnt[d.w], 1); if (sl < CAP) bucket[d.w * CAP + sl] = s.w;
        }
        if (t == 0) { // tail (E%4)
            for (int e = E4 * 4; e < E; ++e) {
                atomicAdd(&deg_out[src[e]], 1);
                int d = dst[e];
                int sl = atomicAdd(&cnt[d], 1);
                if (sl < CAP) bucket[d * CAP + sl] = src[e];
            }
        }
    }
}

// ---------------- agg1: bucket pull, inline norms, fused ReLU epilogue ----------------
__global__ __launch_bounds__(256) void k_agg1(const int* __restrict__ cnt,
                                              const int* __restrict__ deg_out,
                                              const int* __restrict__ bucket,
                                              const float* __restrict__ P,
                                              const float* __restrict__ b1,
                                              float* __restrict__ h1s) {
    int r = blockIdx.x * 8 + (threadIdx.x >> 5);
    int j = threadIdx.x & 31;
    int deg = cnt[r];
    const int* bk = bucket + (size_t)r * CAP;
    float sA = 0.0f, sB = 0.0f;
    int e = 0;
    for (; e + 3 < deg; e += 4) {
        int s0 = bk[e], s1 = bk[e + 1], s2 = bk[e + 2], s3 = bk[e + 3];
        float w0 = rsqrtf((float)deg_out[s0]), w1 = rsqrtf((float)deg_out[s1]);
        float w2 = rsqrtf((float)deg_out[s2]), w3 = rsqrtf((float)deg_out[s3]);
        sA += w0 * P[(size_t)s0 * H1 + j] + w1 * P[(size_t)s1 * H1 + j];
        sB += w2 * P[(size_t)s2 * H1 + j] + w3 * P[(size_t)s3 * H1 + j];
    }
    for (; e < deg; ++e) {
        int s0 = bk[e];
        sA += rsqrtf((float)deg_out[s0]) * P[(size_t)s0 * H1 + j];
    }
    float h = fmaxf((sA + sB) * rsqrtf((float)deg) + b1[j], 0.0f);
    h1s[(size_t)r * H1 + j] = h * rsqrtf((float)deg_out[r]);
}

// ---------------- agg2: bucket pull + inline norm + fused mu/logvar projection ------
__global__ __launch_bounds__(256) void k_agg2(const int* __restrict__ cnt,
                                              const int* __restrict__ bucket,
                                              const float* __restrict__ h1s,
                                              const float* __restrict__ W2, const float* __restrict__ b2,
                                              const float* __restrict__ W3, const float* __restrict__ b3,
                                              float* __restrict__ mu, float* __restrict__ lv) {
    __shared__ float W2l[H1 * H2], W3l[H1 * H2];
    __shared__ float S[8][H1];
    int tid = threadIdx.x;
    for (int t = tid; t < H1 * H2; t += 256) { W2l[t] = W2[t]; W3l[t] = W3[t]; }

    int r0 = blockIdx.x * 8;
    int rl = tid >> 5, j = tid & 31;
    int r = r0 + rl;
    int deg = cnt[r];
    const int* bk = bucket + (size_t)r * CAP;
    float sA = 0.0f, sB = 0.0f;
    int e = 0;
    for (; e + 3 < deg; e += 4) {
        int s0 = bk[e], s1 = bk[e + 1], s2 = bk[e + 2], s3 = bk[e + 3];
        sA += h1s[(size_t)s0 * H1 + j] + h1s[(size_t)s1 * H1 + j];
        sB += h1s[(size_t)s2 * H1 + j] + h1s[(size_t)s3 * H1 + j];
    }
    for (; e < deg; ++e) sA += h1s[(size_t)bk[e] * H1 + j];
    S[rl][j] = (sA + sB) * rsqrtf((float)deg);
    __syncthreads();

    int rr = tid >> 5;
    int c = tid & 15;
    bool is_lv = (tid & 16) != 0;
    const float* W = is_lv ? W3l : W2l;
    float acc = is_lv ? b3[c] : b2[c];
#pragma unroll
    for (int k = 0; k < H1; ++k) acc += S[rr][k] * W[k * H2 + c];
    float* o = is_lv ? lv : mu;
    o[(size_t)(r0 + rr) * H2 + c] = acc;
}

// ---------------- adj = mu @ mu^T, 128x256 tile (R10 shape) + NT stores ------------
#define TI 128
#define TJ 256
__global__ __launch_bounds__(256, 2) void k_adj(const float* __restrict__ mu, float* __restrict__ out) {
    __shared__ float Alt[H2][TI]; // k-major
    __shared__ float Blt[H2][TJ];
    int tid = threadIdx.x;
    int i0 = blockIdx.y * TI;
    int j0 = blockIdx.x * TJ;

    {
        int row = tid >> 1;
        int h8  = (tid & 1) * 8;
        float4 a0 = *(const float4*)&mu[(size_t)(i0 + row) * H2 + h8];
        float4 a1 = *(const float4*)&mu[(size_t)(i0 + row) * H2 + h8 + 4];
        Alt[h8 + 0][row] = a0.x; Alt[h8 + 1][row] = a0.y; Alt[h8 + 2][row] = a0.z; Alt[h8 + 3][row] = a0.w;
        Alt[h8 + 4][row] = a1.x; Alt[h8 + 5][row] = a1.y; Alt[h8 + 6][row] = a1.z; Alt[h8 + 7][row] = a1.w;
        float4 b0 = *(const float4*)&mu[(size_t)(j0 + tid) * H2 + 0];
        float4 b1 = *(const float4*)&mu[(size_t)(j0 + tid) * H2 + 4];
        float4 b2 = *(const float4*)&mu[(size_t)(j0 + tid) * H2 + 8];
        float4 b3 = *(const float4*)&mu[(size_t)(j0 + tid) * H2 + 12];
        Blt[0][tid] = b0.x; Blt[1][tid] = b0.y; Blt[2][tid] = b0.z; Blt[3][tid] = b0.w;
        Blt[4][tid] = b1.x; Blt[5][tid] = b1.y; Blt[6][tid] = b1.z; Blt[7][tid] = b1.w;
        Blt[8][tid] = b2.x; Blt[9][tid] = b2.y; Blt[10][tid] = b2.z; Blt[11][tid] = b2.w;
        Blt[12][tid] = b3.x; Blt[13][tid] = b3.y; Blt[14][tid] = b3.z; Blt[15][tid] = b3.w;
    }
    __syncthreads();

    int tx = tid & 15;
    int ty = tid >> 4;
    floatx2 acc2[8][8] = {};
#pragma unroll 2
    for (int k = 0; k < H2; ++k) {
        floatx4 a0 = *(const floatx4*)&Alt[k][ty * 8];
        floatx4 a1 = *(const floatx4*)&Alt[k][ty * 8 + 4];
        float a[8] = {a0.x, a0.y, a0.z, a0.w, a1.x, a1.y, a1.z, a1.w};
        floatx2 bp[8];
#pragma unroll
        for (int g = 0; g < 4; ++g) {
            floatx4 b = *(const floatx4*)&Blt[k][g * 64 + tx * 4];
            bp[2 * g]     = (floatx2){b.x, b.y};
            bp[2 * g + 1] = (floatx2){b.z, b.w};
        }
#pragma unroll
        for (int ii = 0; ii < 8; ++ii) {
            floatx2 av = (floatx2){a[ii], a[ii]};
#pragma unroll
            for (int jp = 0; jp < 8; ++jp)
                acc2[ii][jp] = __builtin_elementwise_fma(av, bp[jp], acc2[ii][jp]);
        }
    }

    // NT stores: 604 MB streaming output, never re-read — bypass L2 write-allocate
#pragma unroll
    for (int ii = 0; ii < 8; ++ii) {
        size_t row = (size_t)(i0 + ty * 8 + ii);
#pragma unroll
        for (int g = 0; g < 4; ++g) {
            floatx4 v = {acc2[ii][2 * g].x, acc2[ii][2 * g].y,
                         acc2[ii][2 * g + 1].x, acc2[ii][2 * g + 1].y};
            __builtin_nontemporal_store(v, (floatx4*)&out[row * NN + j0 + g * 64 + tx * 4]);
        }
    }
}

extern "C" void kernel_launch(void* const* d_in, const int* in_sizes, int n_in,
                              void* d_out, int out_size, void* d_ws, size_t ws_size,
                              hipStream_t stream) {
    const float* feat = (const float*)d_in[0];
    const int*   src  = (const int*)d_in[1];
    const int*   dst  = (const int*)d_in[2];
    const float* W1   = (const float*)d_in[3];
    const float* b1   = (const float*)d_in[4];
    const float* W2   = (const float*)d_in[5];
    const float* b2   = (const float*)d_in[6];
    const float* W3   = (const float*)d_in[7];
    const float* b3   = (const float*)d_in[8];
    int E = in_sizes[1]; // 405504

    int* iws = (int*)d_ws;
    int* cnt     = iws;                 // [NN]
    int* deg_out = iws + NN;            // [NN]
    int* bucket  = iws + 2 * NN;        // [NN*CAP]
    float* fws = (float*)(iws + 2 * NN + NN * CAP);
    float* P   = fws;                   // [NN*H1]
    float* h1s = fws + NN * H1;         // [NN*H1]

    float* adj = (float*)d_out;             // [NN*NN]
    float* mu  = adj + (size_t)NN * NN;     // [NN*H2]
    float* lv  = mu + (size_t)NN * H2;      // [NN*H2]

    hipMemsetAsync(iws, 0, 2 * NN * sizeof(int), stream); // cnt + deg_out

    int eb4 = ((E >> 2) + 255) / 256;
    k_fused1<<<GEMM_BLOCKS + eb4, 256, 0, stream>>>(feat, W1, P, src, dst,
                                                    cnt, deg_out, bucket, E);
    k_agg1<<<NN / 8, 256, 0, stream>>>(cnt, deg_out, bucket, P, b1, h1s);
    k_agg2<<<NN / 8, 256, 0, stream>>>(cnt, bucket, h1s, W2, b2, W3, b3, mu, lv);

    dim3 grid(NN / TJ, NN / TI);
    k_adj<<<grid, 256, 0, stream>>>(mu, adj);
}